// Round 3
// baseline (400.742 us; speedup 1.0000x reference)
//
#include <hip/hip_runtime.h>
#include <hip/hip_bf16.h>
#include <stdint.h>

#define B_DIM 64
#define S_DIM 512
#define K_DIM 1024   // F_IN
#define N_DIM 1024   // F_OUT
#define M_DIM (B_DIM * S_DIM)  // 32768
#define N_TILES 256            // M_DIM / 128

typedef __attribute__((ext_vector_type(8))) short short8;
typedef __attribute__((ext_vector_type(4))) float floatx4;

__device__ __forceinline__ uint4 pack8_bf16(float4 a, float4 b) {
  union { unsigned short u[8]; uint4 q; } pk;
  __hip_bfloat16 t;
  t = __float2bfloat16(a.x); pk.u[0] = *(unsigned short*)&t;
  t = __float2bfloat16(a.y); pk.u[1] = *(unsigned short*)&t;
  t = __float2bfloat16(a.z); pk.u[2] = *(unsigned short*)&t;
  t = __float2bfloat16(a.w); pk.u[3] = *(unsigned short*)&t;
  t = __float2bfloat16(b.x); pk.u[4] = *(unsigned short*)&t;
  t = __float2bfloat16(b.y); pk.u[5] = *(unsigned short*)&t;
  t = __float2bfloat16(b.z); pk.u[6] = *(unsigned short*)&t;
  t = __float2bfloat16(b.w); pk.u[7] = *(unsigned short*)&t;
  return pk.q;
}

// ---------------------------------------------------------------------------
// prep: blocks 0..511  -> W fp32->bf16
//       blocks 512..767 -> wx[tile][k] = sum_{j=1..16} 0.5^j x[b, s0-j, k]
// wx kept fp32 so the warm-up GEMM reuses the fp32-A main path.
// ---------------------------------------------------------------------------
__global__ __launch_bounds__(256) void prep_kernel(
    const float* __restrict__ W, __hip_bfloat16* __restrict__ Wb,
    const float* __restrict__ x, float* __restrict__ wx) {
  if (blockIdx.x < 512) {
    const size_t t = (size_t)blockIdx.x * 256 + threadIdx.x;
    float4 v0 = *(const float4*)(W + t * 8);
    float4 v1 = *(const float4*)(W + t * 8 + 4);
    *(uint4*)(Wb + t * 8) = pack8_bf16(v0, v1);
  } else {
    const int t = blockIdx.x - 512;  // tile 0..255
    const int b = t >> 2;
    const int c = t & 3;             // s0 = c*128
    const int k4 = threadIdx.x * 4;
    float4 acc = {0.f, 0.f, 0.f, 0.f};
    if (c != 0) {
      const float* base = x + ((size_t)b * S_DIM + c * 128) * K_DIM + k4;
      float wgt = 0.5f;
      #pragma unroll
      for (int j = 1; j <= 16; ++j) {
        float4 v = *(const float4*)(base - (size_t)j * K_DIM);
        acc.x += wgt * v.x; acc.y += wgt * v.y;
        acc.z += wgt * v.z; acc.w += wgt * v.w;
        wgt *= 0.5f;
      }
    }
    *(float4*)(wx + (size_t)t * K_DIM + k4) = acc;
  }
}

// ---------------------------------------------------------------------------
// bf16 NT GEMM, 128x128 tile, BK=64, 4 waves of 64x64, DOUBLE-BUFFERED LDS,
// one barrier per K-step. A is fp32 in global (x itself): issue A(t+1) reg
// loads + B(t+1) global_load_lds into buf^1 BEFORE the MFMA block, cvt +
// swizzled ds_write A(t+1) AFTER it (T14 issue-early/write-late). B keeps
// async direct-to-LDS with source-side k-slot swizzle; A swizzles at the
// ds_write destination. Swizzle: physical slot = logical ^ (row&7).
// MAIN: fused EMA-scan epilogue (scan(x)@W^T == scan(x@W^T), linearity).
// ---------------------------------------------------------------------------
template <bool MAIN>
__global__ __launch_bounds__(256) void gemm_tmpl(
    const float* __restrict__ Af,           // fp32 A: x (MAIN) or wx
    const __hip_bfloat16* __restrict__ Bw,  // [N, K] bf16
    float* __restrict__ out,
    const float* __restrict__ warm) {       // wy [256, N] (MAIN only)
  __shared__ __hip_bfloat16 lA[2][128 * 64];  // 2 x 16 KB
  __shared__ __hip_bfloat16 lB[2][128 * 64];  // 2 x 16 KB
  __shared__ float hbuf[128];

  const int tid  = threadIdx.x;
  const int lane = tid & 63;
  const int w    = tid >> 6;        // wave 0..3
  const int wm   = (w >> 1) * 64;
  const int wn   = (w & 1) * 64;
  const int quad = lane >> 4;
  const int l15  = lane & 15;
  const int r7   = l15 & 7;

  int m0, n0;
  if (MAIN) {
    const int bi    = blockIdx.x;   // 0..2047
    const int xcd   = bi & 7;
    const int local = bi >> 3;
    m0 = (xcd * 32 + (local >> 3)) * 128;
    n0 = (local & 7) * 128;
  } else {
    m0 = (blockIdx.x >> 3) * 128;   // 0..1
    n0 = (blockIdx.x & 7) * 128;
  }

  // Per-thread staging geometry: chunk c = tid + p*256 (p=0..3),
  // row r = c>>3, logical k-chunk q = c&7 (8 bf16 elems = 16 B).
  float4 areg[4][2];

  floatx4 acc[4][4] = {};

  // ---- prologue: tile 0 ----
  #pragma unroll
  for (int p = 0; p < 4; ++p) {
    int c = tid + p * 256, r = c >> 3, q = c & 7;
    const float* ga = Af + (size_t)(m0 + r) * K_DIM + q * 8;
    areg[p][0] = *(const float4*)ga;
    areg[p][1] = *(const float4*)(ga + 4);
  }
  #pragma unroll
  for (int p = 0; p < 4; ++p) {
    int c = tid + p * 256, r = c >> 3, slot = c & 7;
    int kc = (slot ^ (r & 7)) * 8;
    const __hip_bfloat16* gb = Bw + (size_t)(n0 + r) * K_DIM + kc;
    __builtin_amdgcn_global_load_lds(
        (const __attribute__((address_space(1))) void*)gb,
        (__attribute__((address_space(3))) void*)&lB[0][c * 8], 16, 0, 0);
  }
  #pragma unroll
  for (int p = 0; p < 4; ++p) {
    int c = tid + p * 256, r = c >> 3, q = c & 7;
    *(uint4*)&lA[0][r * 64 + ((q ^ (r & 7)) * 8)] =
        pack8_bf16(areg[p][0], areg[p][1]);
  }
  __syncthreads();

  int cur = 0;
  for (int t = 0; t < 16; ++t) {
    const int k1 = (t + 1) * 64;
    if (t < 15) {
      // issue-early: A(t+1) -> regs, B(t+1) -> other LDS buffer (async)
      #pragma unroll
      for (int p = 0; p < 4; ++p) {
        int c = tid + p * 256, r = c >> 3, q = c & 7;
        const float* ga = Af + (size_t)(m0 + r) * K_DIM + k1 + q * 8;
        areg[p][0] = *(const float4*)ga;
        areg[p][1] = *(const float4*)(ga + 4);
      }
      #pragma unroll
      for (int p = 0; p < 4; ++p) {
        int c = tid + p * 256, r = c >> 3, slot = c & 7;
        int kc = (slot ^ (r & 7)) * 8;
        const __hip_bfloat16* gb = Bw + (size_t)(n0 + r) * K_DIM + k1 + kc;
        __builtin_amdgcn_global_load_lds(
            (const __attribute__((address_space(1))) void*)gb,
            (__attribute__((address_space(3))) void*)&lB[cur ^ 1][c * 8], 16, 0, 0);
      }
    }

    // compute on buf[cur]
    #pragma unroll
    for (int kk = 0; kk < 64; kk += 32) {
      const int q0 = kk >> 3;
      short8 af[4], bfr[4];
      #pragma unroll
      for (int i = 0; i < 4; ++i) {
        af[i]  = *(const short8*)&lA[cur][(wm + i * 16 + l15) * 64 +
                                          (((q0 + quad) ^ r7) * 8)];
        bfr[i] = *(const short8*)&lB[cur][(wn + i * 16 + l15) * 64 +
                                          (((q0 + quad) ^ r7) * 8)];
      }
      #pragma unroll
      for (int i = 0; i < 4; ++i)
        #pragma unroll
        for (int j = 0; j < 4; ++j)
          acc[i][j] = __builtin_amdgcn_mfma_f32_16x16x32_bf16(
              af[i], bfr[j], acc[i][j], 0, 0, 0);
    }

    if (t < 15) {
      // write-late: cvt + swizzled ds_write into the other A buffer
      #pragma unroll
      for (int p = 0; p < 4; ++p) {
        int c = tid + p * 256, r = c >> 3, q = c & 7;
        *(uint4*)&lA[cur ^ 1][r * 64 + ((q ^ (r & 7)) * 8)] =
            pack8_bf16(areg[p][0], areg[p][1]);
      }
    }
    __syncthreads();
    cur ^= 1;
  }

  // C/D layout: col = l15 (n), row = quad*4 + reg (m)  [m89-verified]
  if (MAIN) {
    // fused EMA scan over this block's 128 consecutive s rows (one batch)
    const float fq = (quad == 0) ? 1.f : (quad == 1) ? 0.0625f
                   : (quad == 2) ? 0.00390625f : 2.44140625e-4f;  // 0.5^(4q)
    const int tile = m0 >> 7;
    #pragma unroll
    for (int j = 0; j < 4; ++j) {
      const int colIdx = wn + j * 16 + l15;
      float Wst = 0.f;
      if (w < 2) Wst = warm[(size_t)tile * N_DIM + n0 + colIdx];
      #pragma unroll
      for (int i = 0; i < 4; ++i) {
        const float y0 = acc[i][j][0], y1 = acc[i][j][1];
        const float y2 = acc[i][j][2], y3 = acc[i][j][3];
        const float L0 = 0.5f * y0;
        const float L1 = 0.5f * (L0 + y1);
        const float L2 = 0.5f * (L1 + y2);
        const float L3 = 0.5f * (L2 + y3);
        float P = L3;                       // KS prefix w/ decay 0.5^4
        float t1 = __shfl_up(P, 16);
        if (quad >= 1) P += 0.0625f * t1;
        float t2 = __shfl_up(P, 32);
        if (quad >= 2) P += 0.00390625f * t2;
        float H = __shfl_up(P, 16);
        H = (quad >= 1) ? H : 0.f;
        const float S = H + fq * Wst;
        acc[i][j][0] = L0 + 0.5f    * S;
        acc[i][j][1] = L1 + 0.25f   * S;
        acc[i][j][2] = L2 + 0.125f  * S;
        acc[i][j][3] = L3 + 0.0625f * S;
        const float F = __shfl(P, 48 + l15);          // fragment-total
        Wst = F + 1.52587890625e-05f * Wst;           // + 0.5^16 * prev
      }
      if (w < 2 && quad == 0) hbuf[colIdx] = Wst;     // h at row 63
    }
    __syncthreads();
    if (w >= 2) {  // linear correction: + 0.5^(r+1) * h63
      #pragma unroll
      for (int j = 0; j < 4; ++j) {
        const float Z = hbuf[wn + j * 16 + l15] * fq;
        #pragma unroll
        for (int i = 0; i < 4; ++i) {
          const float fi = (i == 0) ? 1.f
                         : (i == 1) ? 1.52587890625e-05f        // 0.5^16
                         : (i == 2) ? 2.3283064365386963e-10f   // 0.5^32
                                    : 3.552713678800501e-15f;   // 0.5^48
          const float base = fi * Z;
          acc[i][j][0] += 0.5f    * base;
          acc[i][j][1] += 0.25f   * base;
          acc[i][j][2] += 0.125f  * base;
          acc[i][j][3] += 0.0625f * base;
        }
      }
    }
  }

  float* hid = MAIN ? out + B_DIM * N_DIM : out;
  #pragma unroll
  for (int i = 0; i < 4; ++i) {
    #pragma unroll
    for (int j = 0; j < 4; ++j) {
      #pragma unroll
      for (int r = 0; r < 4; ++r) {
        int gm = m0 + wm + i * 16 + quad * 4 + r;
        int gn = n0 + wn + j * 16 + l15;
        float v = acc[i][j][r];
        hid[(size_t)gm * N_DIM + gn] = v;
        if (MAIN && ((gm & (S_DIM - 1)) == (S_DIM - 1))) {
          out[(size_t)(gm >> 9) * N_DIM + gn] = v;    // hk[b, n]
        }
      }
    }
  }
}

extern "C" void kernel_launch(void* const* d_in, const int* in_sizes, int n_in,
                              void* d_out, int out_size, void* d_ws, size_t ws_size,
                              hipStream_t stream) {
  const float* x = (const float*)d_in[0];   // [64, 512, 1024] fp32
  const float* W = (const float*)d_in[1];   // [1024, 1024] fp32
  float* out = (float*)d_out;               // [65536 hk][33.55M hiddens] fp32

  __hip_bfloat16* Wb = (__hip_bfloat16*)d_ws;                  // 2 MB
  float*          wx = (float*)(Wb + (size_t)N_DIM * K_DIM);   // 1 MB
  float*          wy = wx + (size_t)N_TILES * K_DIM;           // 1 MB

  prep_kernel<<<dim3(768), dim3(256), 0, stream>>>(W, Wb, x, wx);
  gemm_tmpl<false><<<dim3(16), dim3(256), 0, stream>>>(wx, Wb, wy, nullptr);
  gemm_tmpl<true><<<dim3((M_DIM / 128) * (N_DIM / 128)), dim3(256), 0, stream>>>(x, Wb, out, wy);
}

// Round 4
// 329.035 us; speedup vs baseline: 1.2179x; 1.2179x over previous
//
#include <hip/hip_runtime.h>
#include <hip/hip_bf16.h>
#include <stdint.h>

#define B_DIM 64
#define S_DIM 512
#define K_DIM 1024   // F_IN
#define N_DIM 1024   // F_OUT
#define M_DIM (B_DIM * S_DIM)  // 32768

typedef __attribute__((ext_vector_type(8))) short short8;
typedef __attribute__((ext_vector_type(4))) float floatx4;

__device__ __forceinline__ uint4 pack8_bf16(float4 a, float4 b) {
  union { unsigned short u[8]; uint4 q; } pk;
  __hip_bfloat16 t;
  t = __float2bfloat16(a.x); pk.u[0] = *(unsigned short*)&t;
  t = __float2bfloat16(a.y); pk.u[1] = *(unsigned short*)&t;
  t = __float2bfloat16(a.z); pk.u[2] = *(unsigned short*)&t;
  t = __float2bfloat16(a.w); pk.u[3] = *(unsigned short*)&t;
  t = __float2bfloat16(b.x); pk.u[4] = *(unsigned short*)&t;
  t = __float2bfloat16(b.y); pk.u[5] = *(unsigned short*)&t;
  t = __float2bfloat16(b.z); pk.u[6] = *(unsigned short*)&t;
  t = __float2bfloat16(b.w); pk.u[7] = *(unsigned short*)&t;
  return pk.q;
}

// ---------------------------------------------------------------------------
// Kernel 1: chunked EMA scan along S on x (fp32) fused with fp32->bf16.
// scan_S(x) @ W^T == scan_S(x @ W^T) (linearity). alpha=0.5 forgets at 0.5^k:
// 16-step warm-up restart is exact to ~1.5e-5 (vs 6.9e-2 threshold).
// Vectorized to 8 features/thread (32B loads, 16B stores): 131072 threads,
// 512 blocks = 2 blocks/CU. Same math per feature as the verified R0 kernel.
// ---------------------------------------------------------------------------
__global__ __launch_bounds__(256) void scan_x_kernel(
    const float* __restrict__ x, __hip_bfloat16* __restrict__ xs) {
  const int t  = blockIdx.x * 256 + threadIdx.x;   // 0..131071
  const int f8 = (t & 127) << 3;                   // feature start 0..1016
  const int c  = (t >> 7) & 15;                    // S-chunk 0..15 (block-uniform)
  const int b  = t >> 11;                          // batch 0..63
  const size_t base = (size_t)b * S_DIM * K_DIM + f8;
  const int s0 = c * 32;

  float4 ha = {0.f, 0.f, 0.f, 0.f};
  float4 hb = {0.f, 0.f, 0.f, 0.f};
  if (c != 0) {                                    // block-uniform branch
    #pragma unroll 8
    for (int s = s0 - 16; s < s0; ++s) {
      const float* p = x + base + (size_t)s * K_DIM;
      float4 va = *(const float4*)p;
      float4 vb = *(const float4*)(p + 4);
      ha.x = 0.5f * (ha.x + va.x); ha.y = 0.5f * (ha.y + va.y);
      ha.z = 0.5f * (ha.z + va.z); ha.w = 0.5f * (ha.w + va.w);
      hb.x = 0.5f * (hb.x + vb.x); hb.y = 0.5f * (hb.y + vb.y);
      hb.z = 0.5f * (hb.z + vb.z); hb.w = 0.5f * (hb.w + vb.w);
    }
  }
  #pragma unroll 8
  for (int s = s0; s < s0 + 32; ++s) {
    const float* p = x + base + (size_t)s * K_DIM;
    float4 va = *(const float4*)p;
    float4 vb = *(const float4*)(p + 4);
    ha.x = 0.5f * (ha.x + va.x); ha.y = 0.5f * (ha.y + va.y);
    ha.z = 0.5f * (ha.z + va.z); ha.w = 0.5f * (ha.w + va.w);
    hb.x = 0.5f * (hb.x + vb.x); hb.y = 0.5f * (hb.y + vb.y);
    hb.z = 0.5f * (hb.z + vb.z); hb.w = 0.5f * (hb.w + vb.w);
    *(uint4*)(xs + base + (size_t)s * K_DIM) = pack8_bf16(ha, hb);
  }
}

// ---------------------------------------------------------------------------
// Kernel 2: W fp32 -> bf16 (1M elements), 8/thread vectorized.
// ---------------------------------------------------------------------------
__global__ __launch_bounds__(256) void conv_w_kernel(
    const float* __restrict__ W, __hip_bfloat16* __restrict__ Wb) {
  const size_t t = (size_t)blockIdx.x * 256 + threadIdx.x;
  float4 v0 = *(const float4*)(W + t * 8);
  float4 v1 = *(const float4*)(W + t * 8 + 4);
  *(uint4*)(Wb + t * 8) = pack8_bf16(v0, v1);
}

// ---------------------------------------------------------------------------
// Kernel 3: bf16 NT GEMM, 128x128 tile, BK=64 (verbatim R0 kernel: measured
// 113 us). XCD swizzle for A-panel L2 locality; LDS k-slot swizzle applied to
// the GLOBAL source address at staging (global_load_lds needs lane-contiguous
// LDS dest) and inverted at ds_read. Conflict-free (measured 0).
// ---------------------------------------------------------------------------
__global__ __launch_bounds__(256) void gemm_kernel(
    const __hip_bfloat16* __restrict__ A,   // [M, K] scanned x
    const __hip_bfloat16* __restrict__ Bw,  // [N, K] W (torch Linear layout)
    float* __restrict__ out) {
  __shared__ __hip_bfloat16 lA[128 * 64];   // 16 KB
  __shared__ __hip_bfloat16 lB[128 * 64];   // 16 KB

  const int tid  = threadIdx.x;
  const int lane = tid & 63;
  const int w    = tid >> 6;        // wave 0..3
  const int wm   = (w >> 1) * 64;   // wave m offset within tile
  const int wn   = (w & 1) * 64;    // wave n offset within tile
  const int quad = lane >> 4;       // 0..3
  const int l15  = lane & 15;
  const int r7   = l15 & 7;         // == (fragment row) & 7 (wm, i*16 are mult of 8)

  const int bi    = blockIdx.x;     // 0..2047
  const int xcd   = bi & 7;
  const int local = bi >> 3;        // 0..255
  const int m0 = (xcd * 32 + (local >> 3)) * 128;
  const int n0 = (local & 7) * 128;

  floatx4 acc[4][4] = {};

  for (int k0 = 0; k0 < K_DIM; k0 += 64) {
    #pragma unroll
    for (int p = 0; p < 4; ++p) {
      int c    = tid + p * 256;     // 16-B chunk id 0..1023
      int r    = c >> 3;            // tile row 0..127
      int slot = c & 7;             // physical k-slot in LDS row
      int kc   = (slot ^ (r & 7)) * 8;  // swizzled global k-chunk (bf16 elems)
      const __hip_bfloat16* ga = A  + (size_t)(m0 + r) * K_DIM + k0 + kc;
      const __hip_bfloat16* gb = Bw + (size_t)(n0 + r) * K_DIM + k0 + kc;
      __builtin_amdgcn_global_load_lds(
          (const __attribute__((address_space(1))) void*)ga,
          (__attribute__((address_space(3))) void*)&lA[c * 8], 16, 0, 0);
      __builtin_amdgcn_global_load_lds(
          (const __attribute__((address_space(1))) void*)gb,
          (__attribute__((address_space(3))) void*)&lB[c * 8], 16, 0, 0);
    }
    __syncthreads();

    #pragma unroll
    for (int kk = 0; kk < 64; kk += 32) {
      const int q0 = kk >> 3;       // logical chunk base for this sub-step
      short8 af[4], bfr[4];
      #pragma unroll
      for (int i = 0; i < 4; ++i) {
        af[i]  = *(const short8*)&lA[(wm + i * 16 + l15) * 64 +
                                     (((q0 + quad) ^ r7) * 8)];
        bfr[i] = *(const short8*)&lB[(wn + i * 16 + l15) * 64 +
                                     (((q0 + quad) ^ r7) * 8)];
      }
      #pragma unroll
      for (int i = 0; i < 4; ++i)
        #pragma unroll
        for (int j = 0; j < 4; ++j)
          acc[i][j] = __builtin_amdgcn_mfma_f32_16x16x32_bf16(
              af[i], bfr[j], acc[i][j], 0, 0, 0);
    }
    __syncthreads();
  }

  // Epilogue: C/D layout col=lane&15 (n), row=quad*4+reg (m)  [m89-verified]
  float* hid = out + B_DIM * N_DIM;  // hiddens after hk (65536 floats)
  #pragma unroll
  for (int i = 0; i < 4; ++i) {
    #pragma unroll
    for (int j = 0; j < 4; ++j) {
      #pragma unroll
      for (int r = 0; r < 4; ++r) {
        int gm = m0 + wm + i * 16 + quad * 4 + r;
        int gn = n0 + wn + j * 16 + l15;
        float v = acc[i][j][r];
        hid[(size_t)gm * N_DIM + gn] = v;
        if ((gm & (S_DIM - 1)) == (S_DIM - 1)) {     // s == 511 -> hk row
          out[(size_t)(gm >> 9) * N_DIM + gn] = v;   // hk[b, n]
        }
      }
    }
  }
}

extern "C" void kernel_launch(void* const* d_in, const int* in_sizes, int n_in,
                              void* d_out, int out_size, void* d_ws, size_t ws_size,
                              hipStream_t stream) {
  const float* x = (const float*)d_in[0];   // [64, 512, 1024] fp32
  const float* W = (const float*)d_in[1];   // [1024, 1024] fp32
  float* out = (float*)d_out;               // [65536 hk][33.55M hiddens] fp32

  __hip_bfloat16* xs = (__hip_bfloat16*)d_ws;
  __hip_bfloat16* Wb = (__hip_bfloat16*)((char*)d_ws + (size_t)M_DIM * K_DIM * 2);

  scan_x_kernel<<<dim3(131072 / 256), dim3(256), 0, stream>>>(x, xs);
  conv_w_kernel<<<dim3((N_DIM * K_DIM) / (256 * 8)), dim3(256), 0, stream>>>(W, Wb);
  gemm_kernel<<<dim3((M_DIM / 128) * (N_DIM / 128)), dim3(256), 0, stream>>>(xs, Wb, out);
}